// Round 3
// baseline (218.458 us; speedup 1.0000x reference)
//
#include <hip/hip_runtime.h>

// HOG for (64,1,512,512) f32 input, skimage-compatible:
//   orientations=9, pixels_per_cell=8, cells_per_block=2, L2-Hys.
// Two kernels:
//   1) per-cell 9-bin orientation histograms -> d_ws  (B*64*64*9 floats)
//   2) 2x2-cell sliding-block L2-Hys normalization -> d_out (B*63*63*36 floats)

#define ORIENT 9
#define CELLPX 8
#define IMH 512
#define IMW 512
#define NCR 64           // cells per row  (512/8)
#define NCC 64           // cells per col
#define NBR 63           // blocks per row (64-2+1)
#define NBC 63
#define NIMG 64

// ---------------------------------------------------------------------------
// Kernel 1: cell histograms.
// block = (64, 8): 64-wide x 8-tall pixel strip = 8 cells of one image row.
// grid  = (512/64=8, 512/8=64, B=64)
// ---------------------------------------------------------------------------
__global__ __launch_bounds__(512) void hog_cell_hist(const float* __restrict__ img,
                                                     float* __restrict__ hist) {
    __shared__ float lhist[CELLPX * ORIENT];  // 8 cells x 9 bins
    const int tx = threadIdx.x;               // 0..63 (column within strip)
    const int ty = threadIdx.y;               // 0..7  (row within strip)
    const int tid = ty * 64 + tx;

    if (tid < CELLPX * ORIENT) lhist[tid] = 0.0f;
    __syncthreads();

    const int c = blockIdx.x * 64 + tx;
    const int r = blockIdx.y * 8 + ty;
    const int b = blockIdx.z;
    const float* im = img + (size_t)b * IMH * IMW;

    // skimage central differences, zero at borders
    float gr = 0.0f, gc = 0.0f;
    if (r > 0 && r < IMH - 1)
        gr = im[(size_t)(r + 1) * IMW + c] - im[(size_t)(r - 1) * IMW + c];
    if (c > 0 && c < IMW - 1)
        gc = im[(size_t)r * IMW + c + 1] - im[(size_t)r * IMW + c - 1];

    float mag = sqrtf(gr * gr + gc * gc);
    // unsigned orientation in [0, 180).  NOTE: fmodf is load-bearing — for
    // border rows gr==+0 and atan2f(+0, gc<0)*57.2957795f == exactly 180.0f,
    // which must map to bin 0 (fmodf(180,180)=0), matching JAX's 180%180==0.
    float ori = atan2f(gr, gc) * 57.29577951308232f;  // degrees
    ori = fmodf(ori, 180.0f);
    if (ori < 0.0f) ori += 180.0f;
    int bin = (int)(ori / 20.0f);   // true division: matches XLA's ori/bin_width
    bin = bin > (ORIENT - 1) ? (ORIENT - 1) : bin;

    atomicAdd(&lhist[(tx >> 3) * ORIENT + bin], mag);
    __syncthreads();

    if (tid < CELLPX * ORIENT) {
        const int cell = tid / ORIENT;       // which of the 8 cells in this strip
        const int o    = tid % ORIENT;
        const int cellRow = blockIdx.y;
        const int cellCol = blockIdx.x * 8 + cell;
        hist[(((size_t)b * NCR + cellRow) * NCC + cellCol) * ORIENT + o] =
            lhist[tid] * (1.0f / 64.0f);     // /(CELL*CELL), exact pow2
    }
}

// ---------------------------------------------------------------------------
// Kernel 2: sliding 2x2 block gather + L2-Hys normalize.
// One thread per (image, block_row, block_col) descriptor -> 36 outputs.
// Output layout == reference reshape of (B, nbr, nbc, 2, 2, 9).
// ---------------------------------------------------------------------------
__global__ __launch_bounds__(256) void hog_block_norm(const float* __restrict__ hist,
                                                      float* __restrict__ out) {
    const int total = NIMG * NBR * NBC;
    int t = blockIdx.x * blockDim.x + threadIdx.x;
    if (t >= total) return;

    const int bc = t % NBC;
    const int br = (t / NBC) % NBR;
    const int b  = t / (NBC * NBR);

    float v[36];
    float s = 0.0f;
#pragma unroll
    for (int i = 0; i < 2; ++i) {
        // cells (br+i, bc) and (br+i, bc+1) are 18 contiguous floats
        const float* row = hist + (((size_t)b * NCR + br + i) * NCC + bc) * ORIENT;
#pragma unroll
        for (int k = 0; k < 18; ++k) {
            float h = row[k];
            v[i * 18 + k] = h;               // (i, j, o) flat = i*18 + j*9 + o
            s += h * h;
        }
    }
    const float n1 = sqrtf(s + 1e-10f);      // EPS^2 = 1e-10
    float s2 = 0.0f;
#pragma unroll
    for (int k = 0; k < 36; ++k) {
        float x = fminf(v[k] / n1, 0.2f);
        v[k] = x;
        s2 += x * x;
    }
    const float n2 = sqrtf(s2 + 1e-10f);

    float* o = out + (size_t)t * 36;
#pragma unroll
    for (int k = 0; k < 36; ++k) o[k] = v[k] / n2;
}

// ---------------------------------------------------------------------------
extern "C" void kernel_launch(void* const* d_in, const int* in_sizes, int n_in,
                              void* d_out, int out_size, void* d_ws, size_t ws_size,
                              hipStream_t stream) {
    const float* x  = (const float*)d_in[0];   // (64,1,512,512) f32
    float* out      = (float*)d_out;           // (64, 63*63*36)  f32
    float* hist     = (float*)d_ws;            // B*64*64*9 floats = 9.44 MB

    dim3 b1(64, 8, 1);
    dim3 g1(IMW / 64, IMH / 8, NIMG);
    hipLaunchKernelGGL(hog_cell_hist, g1, b1, 0, stream, x, hist);

    const int total = NIMG * NBR * NBC;        // 254016
    dim3 b2(256, 1, 1);
    dim3 g2((total + 255) / 256, 1, 1);
    hipLaunchKernelGGL(hog_block_norm, g2, b2, 0, stream, hist, out);
}

// Round 5
// 188.387 us; speedup vs baseline: 1.1596x; 1.1596x over previous
//
#include <hip/hip_runtime.h>

// HOG (64,1,512,512) f32, skimage-compatible: orientations=9, cell=8, block=2x2, L2-Hys.
// K1: per-cell 9-bin hist -> d_ws (64*64*64*9 f32). One thread = 8 px (one cell-row).
// K2: 2x2 sliding-block L2-Hys -> d_out (64*63*63*36 f32).

#define ORIENT 9
#define IMH 512
#define IMW 512
#define NCR 64
#define NCC 64
#define NBR 63
#define NBC 63
#define NIMG 64

// ---------------------------------------------------------------------------
// Kernel 1. block (32,8)=256 thr: 32 cells wide x 8 rows = one cell-strip.
// grid (512/256=2, 64, 64). Thread (tx,ty): pixels (r=by*8+ty, c0=bx*256+tx*8 .. +7),
// all in cell (by, bx*32+tx).
// ---------------------------------------------------------------------------
__global__ __launch_bounds__(256) void hog_cell_hist(const float* __restrict__ img,
                                                     float* __restrict__ hist) {
    __shared__ float lh[32 * ORIENT];           // 288 floats
    const int tx = threadIdx.x;                 // 0..31  (cell in strip)
    const int ty = threadIdx.y;                 // 0..7   (row in cell)
    const int tid = ty * 32 + tx;

    lh[tid] = 0.f;
    if (tid < 32) lh[tid + 256] = 0.f;
    __syncthreads();

    const int c0 = blockIdx.x * 256 + tx * 8;
    const int r  = blockIdx.y * 8 + ty;
    const float* im = img + (size_t)blockIdx.z * (IMH * IMW) + (size_t)r * IMW + c0;

    // c0 is a multiple of 8 floats -> 32B aligned: float4 loads are safe.
    const float4* imv = (const float4*)im;
    float4 a0 = imv[0], b0 = imv[1];            // row r  [c0..c0+7]
    float4 am = {0,0,0,0}, bm = {0,0,0,0};      // row r-1
    float4 ap = {0,0,0,0}, bp = {0,0,0,0};      // row r+1
    const bool rin = (r > 0) && (r < IMH - 1);
    if (r > 0)       { const float4* p = (const float4*)(im - IMW); am = p[0]; bm = p[1]; }
    if (r < IMH - 1) { const float4* p = (const float4*)(im + IMW); ap = p[0]; bp = p[1]; }
    const float left  = (c0 > 0)       ? im[-1] : 0.f;
    const float right = (c0 + 8 < IMW) ? im[8]  : 0.f;

    // constant-indexed after unroll -> registers (no scratch)
    float rv[10] = {left, a0.x, a0.y, a0.z, a0.w, b0.x, b0.y, b0.z, b0.w, right};
    float pv[8]  = {ap.x, ap.y, ap.z, ap.w, bp.x, bp.y, bp.z, bp.w};
    float mv[8]  = {am.x, am.y, am.z, am.w, bm.x, bm.y, bm.z, bm.w};

    float* cellh = &lh[tx * ORIENT];
#pragma unroll
    for (int j = 0; j < 8; ++j) {
        const float gr = rin ? (pv[j] - mv[j]) : 0.f;                       // central diff rows
        const bool cin = (c0 + j > 0) && (c0 + j < IMW - 1);
        const float gc = cin ? (rv[j + 2] - rv[j]) : 0.f;                   // central diff cols
        const float mag = sqrtf(gr * gr + gc * gc);
        // degrees(atan2) % 180, floor-mod. |ori| <= 180.0000x so two predicated
        // fixups are bit-identical to fmodf+cond-add (incl. ori==180 -> 0,
        // matching JAX 180%180==0 for the gr==+0, gc<0 border case).
        float ori = atan2f(gr, gc) * 57.29577951308232f;
        ori = (ori >= 180.0f) ? ori - 180.0f : ori;
        ori = (ori <   0.0f) ? ori + 180.0f : ori;
        int bin = (int)(ori / 20.0f);            // true division: matches XLA
        bin = bin > (ORIENT - 1) ? (ORIENT - 1) : bin;
        atomicAdd(&cellh[bin], mag);
    }
    __syncthreads();

    // 288 contiguous floats: hist[b][by][bx*32 .. bx*32+31][0..8]
    float* hrow = hist + (((size_t)blockIdx.z * NCR + blockIdx.y) * NCC + blockIdx.x * 32) * ORIENT;
    hrow[tid] = lh[tid] * (1.f / 64.f);
    if (tid < 32) hrow[tid + 256] = lh[tid + 256] * (1.f / 64.f);
}

// ---------------------------------------------------------------------------
// Kernel 2: one thread per (image, br, bc) descriptor -> 36 outputs.
// 2 true divisions total (reciprocals), float4 stores (t*144B is 16B-aligned).
// ---------------------------------------------------------------------------
__global__ __launch_bounds__(256) void hog_block_norm(const float* __restrict__ hist,
                                                      float* __restrict__ out) {
    const int total = NIMG * NBR * NBC;
    int t = blockIdx.x * blockDim.x + threadIdx.x;
    if (t >= total) return;

    const int bc = t % NBC;
    const int br = (t / NBC) % NBR;
    const int b  = t / (NBC * NBR);

    float v[36];
    float s = 0.f;
#pragma unroll
    for (int i = 0; i < 2; ++i) {
        const float* row = hist + (((size_t)b * NCR + br + i) * NCC + bc) * ORIENT;
#pragma unroll
        for (int k = 0; k < 18; ++k) { float h = row[k]; v[i * 18 + k] = h; s += h * h; }
    }
    const float r1 = 1.0f / sqrtf(s + 1e-10f);    // EPS^2
    float s2 = 0.f;
#pragma unroll
    for (int k = 0; k < 36; ++k) {
        float x = fminf(v[k] * r1, 0.2f);
        v[k] = x;
        s2 += x * x;
    }
    const float r2 = 1.0f / sqrtf(s2 + 1e-10f);

    float4* o = (float4*)(out + (size_t)t * 36);
#pragma unroll
    for (int k = 0; k < 9; ++k)
        o[k] = make_float4(v[4*k] * r2, v[4*k+1] * r2, v[4*k+2] * r2, v[4*k+3] * r2);
}

// ---------------------------------------------------------------------------
extern "C" void kernel_launch(void* const* d_in, const int* in_sizes, int n_in,
                              void* d_out, int out_size, void* d_ws, size_t ws_size,
                              hipStream_t stream) {
    const float* x = (const float*)d_in[0];
    float* out  = (float*)d_out;
    float* hist = (float*)d_ws;                 // 64*64*64*9 f32 = 9.44 MB

    dim3 b1(32, 8, 1);
    dim3 g1(IMW / 256, IMH / 8, NIMG);          // (2, 64, 64)
    hipLaunchKernelGGL(hog_cell_hist, g1, b1, 0, stream, x, hist);

    const int total = NIMG * NBR * NBC;         // 254016
    dim3 b2(256, 1, 1);
    dim3 g2((total + 255) / 256, 1, 1);
    hipLaunchKernelGGL(hog_block_norm, g2, b2, 0, stream, hist, out);
}